// Round 24
// baseline (54.396 us; speedup 1.0000x reference)
//
#include <hip/hip_runtime.h>
#include <hip/hip_fp16.h>

#define B_ 16
#define QN 256
#define KN 256
#define DN 256
#define HN 256

#define LOG2E 1.4426950408889634f
#define TWOLOG2E 2.8853900817779268f  // exp2(x*this) = e^{2x}

__device__ inline float readlane_f(float v, int l) {
    return __uint_as_float(__builtin_amdgcn_readlane(__float_as_uint(v), l));
}

__device__ inline float2 h2f(unsigned u) {
    union { unsigned u32; __half2 h2; } cv;
    cv.u32 = u;
    return __half22float2(cv.h2);
}

// ---------------- Kernel A (fused): projections + exp ----------------
// R21 verbatim: 16 rows/block; thread = 8 rows x 2 h; 2-stage W + x prefetch
// (named regs); exp2 epilogue. ek stored FP16 in [h/8][k][8] octets; eq f32.
__global__ __launch_bounds__(256, 2) void proj_kernel(const float* __restrict__ Xq,
                                                      const float* __restrict__ Xk,
                                                      const float* __restrict__ Wq,
                                                      const float* __restrict__ Wk,
                                                      float* __restrict__ EQ,
                                                      __half* __restrict__ EKT,
                                                      float scale) {
    const int nb = (int)gridDim.x >> 1;
    int blk = blockIdx.x;
    const bool is_q = blk < nb;
    const float* X;
    const float* W;
    if (is_q) { X = Xq; W = Wq; }
    else      { X = Xk; W = Wk; blk -= nb; }
    const int row0 = blk * 16;

    __shared__ float xl[16][260];
    __shared__ float trans[16][260];
    const int tid = threadIdx.x;

    {
        const float4* src = (const float4*)(X + (size_t)row0 * DN);
#pragma unroll
        for (int i = 0; i < 4; ++i) {
            int idx = tid + 256 * i;
            int r = idx >> 6, c = (idx & 63) << 2;
            *(float4*)&xl[r][c] = src[idx];
        }
    }
    __syncthreads();

    const int wvid = tid >> 6;
    const int rbase = (wvid >> 1) << 3;
    const int hh2 = ((wvid & 1) << 7) | ((tid & 63) << 1);

    float2 acc[8];
#pragma unroll
    for (int r = 0; r < 8; ++r) acc[r] = make_float2(0.f, 0.f);

#define LOADW2(WS, D0)                                                         \
    do {                                                                       \
        _Pragma("unroll") for (int j = 0; j < 4; ++j)                          \
            WS[j] = *(const float2*)&W[(size_t)((D0) + j) * HN + hh2];         \
    } while (0)

#define LOADX8(XS, D0)                                                         \
    do {                                                                       \
        _Pragma("unroll") for (int r = 0; r < 8; ++r)                          \
            XS[r] = *(const float4*)&xl[rbase + r][(D0)];                      \
    } while (0)

#define COMP2(WS, XS)                                                          \
    do {                                                                       \
        _Pragma("unroll") for (int r = 0; r < 8; ++r) {                        \
            acc[r].x = fmaf(XS[r].x, WS[0].x, acc[r].x);                       \
            acc[r].y = fmaf(XS[r].x, WS[0].y, acc[r].y);                       \
            acc[r].x = fmaf(XS[r].y, WS[1].x, acc[r].x);                       \
            acc[r].y = fmaf(XS[r].y, WS[1].y, acc[r].y);                       \
            acc[r].x = fmaf(XS[r].z, WS[2].x, acc[r].x);                       \
            acc[r].y = fmaf(XS[r].z, WS[2].y, acc[r].y);                       \
            acc[r].x = fmaf(XS[r].w, WS[3].x, acc[r].x);                       \
            acc[r].y = fmaf(XS[r].w, WS[3].y, acc[r].y);                       \
        }                                                                      \
    } while (0)

    {
        float2 w0[4], w1[4];
        float4 xA[8], xB[8];
        LOADX8(xA, 0);
        LOADX8(xB, 4);
        LOADW2(w0, 0);
        LOADW2(w1, 4);
        for (int d0 = 0; d0 < DN - 8; d0 += 8) {
            COMP2(w0, xA); LOADX8(xA, d0 + 8);  LOADW2(w0, d0 + 8);
            COMP2(w1, xB); LOADX8(xB, d0 + 12); LOADW2(w1, d0 + 12);
        }
        COMP2(w0, xA);
        COMP2(w1, xB);
    }

#pragma unroll
    for (int r = 0; r < 8; ++r) {
        acc[r].x = __builtin_amdgcn_exp2f(acc[r].x * scale);
        acc[r].y = __builtin_amdgcn_exp2f(acc[r].y * scale);
    }

    if (is_q) {
#pragma unroll
        for (int r = 0; r < 8; ++r)
            *(float2*)&EQ[(size_t)(row0 + rbase + r) * HN + hh2] = acc[r];
    } else {
#pragma unroll
        for (int r = 0; r < 8; ++r)
            *(float2*)&trans[rbase + r][hh2] = acc[r];
        __syncthreads();
        const int b = row0 >> 8, kloc0 = row0 & 255;
        __half* dstb = EKT + (size_t)b * 32 * 256 * 8;
#pragma unroll
        for (int i = 0; i < 4; ++i) {
            int idx = i * 256 + tid;
            int u4 = (idx & 1) << 2;
            int kj = (idx >> 1) & 15;
            int h0 = idx >> 5;
            float4 val = *(const float4*)&trans[kj][h0 * 8 + u4];
            __half2 lo = __floats2half2_rn(val.x, val.y);
            __half2 hi = __floats2half2_rn(val.z, val.w);
            __half2* dst = (__half2*)&dstb[((size_t)h0 * 256 + kloc0 + kj) * 8 + u4];
            dst[0] = lo;
            dst[1] = hi;
        }
    }
}

// ------------- Kernel B (fused): score + masked softmax + PV ----------------
// R21 body verbatim (best measured: 53.0 us total) EXCEPT the score PASS uses
// a 4-DEEP named k-prefetch (kr0..kr3): load lead ~3 windows ~300+ cyc, which
// covers L2 latency (2-deep's ~64-128 cyc lead did not). +8 VGPR, still << 64
// cap at 8 blocks/CU. eq/wv staged f32 in LDS; ek fp16 octets (1 b128/window);
// V f32. Masked p == 0 exactly; LDS combine + wave softmax + O-reduce as before.
__global__ __launch_bounds__(256, 8) void attn_kernel(const float* __restrict__ EQ,
                                                      const __half* __restrict__ EKT,
                                                      const float* __restrict__ wv,
                                                      const int* __restrict__ lens,
                                                      const float* __restrict__ V,
                                                      float* __restrict__ OUT) {
    const int b = blockIdx.y;
    const int q0 = blockIdx.x * 2;
    const int len = lens[b];

    __shared__ float eq_lds[2][256];    // 2 KB
    __shared__ float wv_lds[256];       // 1 KB
    __shared__ float shbuf[2048];       // 8 KB: score-partials, then O-partials
    __shared__ float maxb[4][2];
    __shared__ float sumb[4][2];

    const int tid = threadIdx.x;
    const int w = tid >> 6, lane = tid & 63;

    {
        if (tid < 128) {
            const float4* src = (const float4*)&EQ[((size_t)b * QN + q0) * HN];
            ((float4*)&eq_lds[0][0])[tid] = src[tid];
        }
        if (tid >= 192)
            *(float4*)&wv_lds[(tid - 192) << 2] = ((const float4*)wv)[tid - 192];
    }
    __syncthreads();

    // ---- score: wave w covers h in [64w, 64w+64); pass j covers k = 64j+lane
    float a00 = 0.f, a01 = 0.f;
    float a10 = 0.f, a11 = 0.f;
    float a20 = 0.f, a21 = 0.f;
    float a30 = 0.f, a31 = 0.f;

    const __half* ekb = EKT + (size_t)b * (32 * 256 * 8) + (size_t)(8 * w) * 2048;

#define WINDOW(KR, H8, A0, A1)                                                   \
    do {                                                                         \
        float2 k01 = h2f((KR).x);                                                \
        float2 k23 = h2f((KR).y);                                                \
        float2 k45 = h2f((KR).z);                                                \
        float2 k67 = h2f((KR).w);                                                \
        float4 wa = *(const float4*)&wv_lds[(H8)];                               \
        float4 wb = *(const float4*)&wv_lds[(H8) + 4];                           \
        float4 qa0 = *(const float4*)&eq_lds[0][(H8)];                           \
        float4 qb0 = *(const float4*)&eq_lds[0][(H8) + 4];                       \
        float4 qa1 = *(const float4*)&eq_lds[1][(H8)];                           \
        float4 qb1 = *(const float4*)&eq_lds[1][(H8) + 4];                       \
        A0 = fmaf(wa.x, __builtin_amdgcn_rcpf(fmaf(qa0.x, k01.x, 1.f)), A0);     \
        A0 = fmaf(wa.y, __builtin_amdgcn_rcpf(fmaf(qa0.y, k01.y, 1.f)), A0);     \
        A0 = fmaf(wa.z, __builtin_amdgcn_rcpf(fmaf(qa0.z, k23.x, 1.f)), A0);     \
        A0 = fmaf(wa.w, __builtin_amdgcn_rcpf(fmaf(qa0.w, k23.y, 1.f)), A0);     \
        A0 = fmaf(wb.x, __builtin_amdgcn_rcpf(fmaf(qb0.x, k45.x, 1.f)), A0);     \
        A0 = fmaf(wb.y, __builtin_amdgcn_rcpf(fmaf(qb0.y, k45.y, 1.f)), A0);     \
        A0 = fmaf(wb.z, __builtin_amdgcn_rcpf(fmaf(qb0.z, k67.x, 1.f)), A0);     \
        A0 = fmaf(wb.w, __builtin_amdgcn_rcpf(fmaf(qb0.w, k67.y, 1.f)), A0);     \
        A1 = fmaf(wa.x, __builtin_amdgcn_rcpf(fmaf(qa1.x, k01.x, 1.f)), A1);     \
        A1 = fmaf(wa.y, __builtin_amdgcn_rcpf(fmaf(qa1.y, k01.y, 1.f)), A1);     \
        A1 = fmaf(wa.z, __builtin_amdgcn_rcpf(fmaf(qa1.z, k23.x, 1.f)), A1);     \
        A1 = fmaf(wa.w, __builtin_amdgcn_rcpf(fmaf(qa1.w, k23.y, 1.f)), A1);     \
        A1 = fmaf(wb.x, __builtin_amdgcn_rcpf(fmaf(qb1.x, k45.x, 1.f)), A1);     \
        A1 = fmaf(wb.y, __builtin_amdgcn_rcpf(fmaf(qb1.y, k45.y, 1.f)), A1);     \
        A1 = fmaf(wb.z, __builtin_amdgcn_rcpf(fmaf(qb1.z, k67.x, 1.f)), A1);     \
        A1 = fmaf(wb.w, __builtin_amdgcn_rcpf(fmaf(qb1.w, k67.y, 1.f)), A1);     \
    } while (0)

#define PASS(J, A0, A1)                                                          \
    do {                                                                         \
        if ((J) * 64 < len) {                                                    \
            const __half* kp = ekb + (size_t)((J) * 64 + lane) * 8;              \
            uint4 kr0 = *(const uint4*)&kp[0];                                   \
            uint4 kr1 = *(const uint4*)&kp[(size_t)1 * 2048];                    \
            uint4 kr2 = *(const uint4*)&kp[(size_t)2 * 2048];                    \
            uint4 kr3 = *(const uint4*)&kp[(size_t)3 * 2048];                    \
            _Pragma("unroll") for (int hw = 0; hw < 8; hw += 4) {                \
                WINDOW(kr0, (w << 6) + (hw + 0) * 8, A0, A1);                    \
                if (hw + 4 < 8) kr0 = *(const uint4*)&kp[(size_t)(hw + 4) * 2048]; \
                WINDOW(kr1, (w << 6) + (hw + 1) * 8, A0, A1);                    \
                if (hw + 5 < 8) kr1 = *(const uint4*)&kp[(size_t)(hw + 5) * 2048]; \
                WINDOW(kr2, (w << 6) + (hw + 2) * 8, A0, A1);                    \
                if (hw + 6 < 8) kr2 = *(const uint4*)&kp[(size_t)(hw + 6) * 2048]; \
                WINDOW(kr3, (w << 6) + (hw + 3) * 8, A0, A1);                    \
                if (hw + 7 < 8) kr3 = *(const uint4*)&kp[(size_t)(hw + 7) * 2048]; \
            }                                                                    \
        }                                                                        \
    } while (0)

    PASS(0, a00, a01);
    PASS(1, a10, a11);
    PASS(2, a20, a21);
    PASS(3, a30, a31);

    // store score partials: shbuf[((w*4 + j)*2 + q)*64 + lane]
    {
        float* sp = &shbuf[(size_t)(w << 3) * 64 + lane];
        sp[0 * 64] = a00; sp[1 * 64] = a01;
        sp[2 * 64] = a10; sp[3 * 64] = a11;
        sp[4 * 64] = a20; sp[5 * 64] = a21;
        sp[6 * 64] = a30; sp[7 * 64] = a31;
    }
    __syncthreads();

    // combine: wave w sums the 4 h-chunk partials for its k-chunk (j = w)
    const bool act = (w * 64) < len;
    float sum0 = 0.f, sum1 = 0.f;
    if (act) {
#pragma unroll
        for (int hc = 0; hc < 4; ++hc) {
            sum0 += shbuf[((hc * 4 + w) * 2 + 0) * 64 + lane];
            sum1 += shbuf[((hc * 4 + w) * 2 + 1) * 64 + lane];
        }
    }
    const bool kvalid = (w * 64 + lane) < len;
    float xs0 = kvalid ? (-2.f * sum0) : -1e6f;
    float xs1 = kvalid ? (-2.f * sum1) : -1e6f;

    float m0 = xs0, m1 = xs1;
#pragma unroll
    for (int off = 32; off; off >>= 1) {
        m0 = fmaxf(m0, __shfl_xor(m0, off, 64));
        m1 = fmaxf(m1, __shfl_xor(m1, off, 64));
    }
    if (lane == 0) { maxb[w][0] = m0; maxb[w][1] = m1; }
    __syncthreads();
    float g0 = fmaxf(fmaxf(maxb[0][0], maxb[1][0]), fmaxf(maxb[2][0], maxb[3][0]));
    float g1 = fmaxf(fmaxf(maxb[0][1], maxb[1][1]), fmaxf(maxb[2][1], maxb[3][1]));

    float p0 = __builtin_amdgcn_exp2f((xs0 - g0) * LOG2E);
    float p1 = __builtin_amdgcn_exp2f((xs1 - g1) * LOG2E);

    float s0 = p0, s1 = p1;
#pragma unroll
    for (int off = 32; off; off >>= 1) {
        s0 += __shfl_xor(s0, off, 64);
        s1 += __shfl_xor(s1, off, 64);
    }
    if (lane == 0) { sumb[w][0] = s0; sumb[w][1] = s1; }
    __syncthreads();
    float t0 = (sumb[0][0] + sumb[1][0]) + (sumb[2][0] + sumb[3][0]);
    float t1 = (sumb[0][1] + sumb[1][1]) + (sumb[2][1] + sumb[3][1]);
    p0 *= 1.f / t0;
    p1 *= 1.f / t1;

    // PV: wave w covers its 64 k rows (clamped to len); 4-deep batched V loads
    float4 op0 = make_float4(0.f, 0.f, 0.f, 0.f);
    float4 op1 = op0;
    if (act) {
        int kmax = len - w * 64;
        if (kmax > 64) kmax = 64;
        const float* vb = V + ((size_t)b * KN + (size_t)w * 64) * DN + (lane << 2);

#define PV_STEP(KK, VV)                                                        \
    do {                                                                       \
        float b0 = readlane_f(p0, (KK));                                       \
        float b1 = readlane_f(p1, (KK));                                       \
        op0.x = fmaf(b0, VV.x, op0.x); op0.y = fmaf(b0, VV.y, op0.y);          \
        op0.z = fmaf(b0, VV.z, op0.z); op0.w = fmaf(b0, VV.w, op0.w);          \
        op1.x = fmaf(b1, VV.x, op1.x); op1.y = fmaf(b1, VV.y, op1.y);          \
        op1.z = fmaf(b1, VV.z, op1.z); op1.w = fmaf(b1, VV.w, op1.w);          \
    } while (0)

        int kk = 0;
        for (; kk + 4 <= kmax; kk += 4) {
            float4 v0 = *(const float4*)&vb[(size_t)(kk + 0) * DN];
            float4 v1 = *(const float4*)&vb[(size_t)(kk + 1) * DN];
            float4 v2 = *(const float4*)&vb[(size_t)(kk + 2) * DN];
            float4 v3 = *(const float4*)&vb[(size_t)(kk + 3) * DN];
            PV_STEP(kk + 0, v0);
            PV_STEP(kk + 1, v1);
            PV_STEP(kk + 2, v2);
            PV_STEP(kk + 3, v3);
        }
        for (; kk < kmax; ++kk) {
            float4 v0 = *(const float4*)&vb[(size_t)kk * DN];
            PV_STEP(kk, v0);
        }
    }
    __syncthreads();   // score-partial reads done; shbuf reused for O-partials
    {
        const int d4 = lane << 2;
        *(float4*)&shbuf[((w << 1) + 0) * 256 + d4] = op0;
        *(float4*)&shbuf[((w << 1) + 1) * 256 + d4] = op1;
    }
    __syncthreads();

    if (tid < 128) {
        const int q = tid >> 6, ln = tid & 63;
        const int d4 = ln << 2;
        float4 r0 = *(const float4*)&shbuf[(0 * 2 + q) * 256 + d4];
        float4 r1 = *(const float4*)&shbuf[(1 * 2 + q) * 256 + d4];
        float4 r2 = *(const float4*)&shbuf[(2 * 2 + q) * 256 + d4];
        float4 r3 = *(const float4*)&shbuf[(3 * 2 + q) * 256 + d4];
        float4 r = make_float4((r0.x + r1.x) + (r2.x + r3.x),
                               (r0.y + r1.y) + (r2.y + r3.y),
                               (r0.z + r1.z) + (r2.z + r3.z),
                               (r0.w + r1.w) + (r2.w + r3.w));
        *(float4*)&OUT[((size_t)b * QN + q0 + q) * DN + d4] = r;
    }
}

extern "C" void kernel_launch(void* const* d_in, const int* in_sizes, int n_in,
                              void* d_out, int out_size, void* d_ws, size_t ws_size,
                              hipStream_t stream) {
    const float* queries = (const float*)d_in[0];
    const float* keys    = (const float*)d_in[1];
    const float* values  = (const float*)d_in[2];
    const int*   lens    = (const int*)d_in[3];
    const float* Wq      = (const float*)d_in[4];
    const float* Wk      = (const float*)d_in[5];
    const float* wv      = (const float*)d_in[6];
    float* out = (float*)d_out;

    float* eq   = (float*)d_ws;                          // [B,Q,H]    4 MB f32
    __half* ekT = (__half*)(eq + (size_t)B_ * QN * HN);  // [B,32,K,8] 2 MB fp16

    proj_kernel<<<(B_ * QN + B_ * KN) / 16, 256, 0, stream>>>(
        queries, keys, Wq, Wk, eq, ekT, TWOLOG2E);

    dim3 gB(QN / 2, B_);
    attn_kernel<<<gB, 256, 0, stream>>>(eq, ekT, wv, lens, values, out);
}

// Round 25
// 52.906 us; speedup vs baseline: 1.0281x; 1.0281x over previous
//
#include <hip/hip_runtime.h>
#include <hip/hip_fp16.h>

#define B_ 16
#define QN 256
#define KN 256
#define DN 256
#define HN 256

#define LOG2E 1.4426950408889634f
#define TWOLOG2E 2.8853900817779268f  // exp2(x*this) = e^{2x}

__device__ inline float readlane_f(float v, int l) {
    return __uint_as_float(__builtin_amdgcn_readlane(__float_as_uint(v), l));
}

__device__ inline float2 h2f(unsigned u) {
    union { unsigned u32; __half2 h2; } cv;
    cv.u32 = u;
    return __half22float2(cv.h2);
}

// ---------------- Kernel A (fused): projections + exp ----------------
// 16 rows/block; thread = 8 rows x 2 h; 2-stage W + x prefetch (named regs);
// exp2 epilogue. ek stored FP16 in [h/8][k][8] octets; eq f32.
__global__ __launch_bounds__(256, 2) void proj_kernel(const float* __restrict__ Xq,
                                                      const float* __restrict__ Xk,
                                                      const float* __restrict__ Wq,
                                                      const float* __restrict__ Wk,
                                                      float* __restrict__ EQ,
                                                      __half* __restrict__ EKT,
                                                      float scale) {
    const int nb = (int)gridDim.x >> 1;
    int blk = blockIdx.x;
    const bool is_q = blk < nb;
    const float* X;
    const float* W;
    if (is_q) { X = Xq; W = Wq; }
    else      { X = Xk; W = Wk; blk -= nb; }
    const int row0 = blk * 16;

    __shared__ float xl[16][260];
    __shared__ float trans[16][260];
    const int tid = threadIdx.x;

    {
        const float4* src = (const float4*)(X + (size_t)row0 * DN);
#pragma unroll
        for (int i = 0; i < 4; ++i) {
            int idx = tid + 256 * i;
            int r = idx >> 6, c = (idx & 63) << 2;
            *(float4*)&xl[r][c] = src[idx];
        }
    }
    __syncthreads();

    const int wvid = tid >> 6;
    const int rbase = (wvid >> 1) << 3;
    const int hh2 = ((wvid & 1) << 7) | ((tid & 63) << 1);

    float2 acc[8];
#pragma unroll
    for (int r = 0; r < 8; ++r) acc[r] = make_float2(0.f, 0.f);

#define LOADW2(WS, D0)                                                         \
    do {                                                                       \
        _Pragma("unroll") for (int j = 0; j < 4; ++j)                          \
            WS[j] = *(const float2*)&W[(size_t)((D0) + j) * HN + hh2];         \
    } while (0)

#define LOADX8(XS, D0)                                                         \
    do {                                                                       \
        _Pragma("unroll") for (int r = 0; r < 8; ++r)                          \
            XS[r] = *(const float4*)&xl[rbase + r][(D0)];                      \
    } while (0)

#define COMP2(WS, XS)                                                          \
    do {                                                                       \
        _Pragma("unroll") for (int r = 0; r < 8; ++r) {                        \
            acc[r].x = fmaf(XS[r].x, WS[0].x, acc[r].x);                       \
            acc[r].y = fmaf(XS[r].x, WS[0].y, acc[r].y);                       \
            acc[r].x = fmaf(XS[r].y, WS[1].x, acc[r].x);                       \
            acc[r].y = fmaf(XS[r].y, WS[1].y, acc[r].y);                       \
            acc[r].x = fmaf(XS[r].z, WS[2].x, acc[r].x);                       \
            acc[r].y = fmaf(XS[r].z, WS[2].y, acc[r].y);                       \
            acc[r].x = fmaf(XS[r].w, WS[3].x, acc[r].x);                       \
            acc[r].y = fmaf(XS[r].w, WS[3].y, acc[r].y);                       \
        }                                                                      \
    } while (0)

    {
        float2 w0[4], w1[4];
        float4 xA[8], xB[8];
        LOADX8(xA, 0);
        LOADX8(xB, 4);
        LOADW2(w0, 0);
        LOADW2(w1, 4);
        for (int d0 = 0; d0 < DN - 8; d0 += 8) {
            COMP2(w0, xA); LOADX8(xA, d0 + 8);  LOADW2(w0, d0 + 8);
            COMP2(w1, xB); LOADX8(xB, d0 + 12); LOADW2(w1, d0 + 12);
        }
        COMP2(w0, xA);
        COMP2(w1, xB);
    }

#pragma unroll
    for (int r = 0; r < 8; ++r) {
        acc[r].x = __builtin_amdgcn_exp2f(acc[r].x * scale);
        acc[r].y = __builtin_amdgcn_exp2f(acc[r].y * scale);
    }

    if (is_q) {
#pragma unroll
        for (int r = 0; r < 8; ++r)
            *(float2*)&EQ[(size_t)(row0 + rbase + r) * HN + hh2] = acc[r];
    } else {
#pragma unroll
        for (int r = 0; r < 8; ++r)
            *(float2*)&trans[rbase + r][hh2] = acc[r];
        __syncthreads();
        const int b = row0 >> 8, kloc0 = row0 & 255;
        __half* dstb = EKT + (size_t)b * 32 * 256 * 8;
#pragma unroll
        for (int i = 0; i < 4; ++i) {
            int idx = i * 256 + tid;
            int u4 = (idx & 1) << 2;
            int kj = (idx >> 1) & 15;
            int h0 = idx >> 5;
            float4 val = *(const float4*)&trans[kj][h0 * 8 + u4];
            __half2 lo = __floats2half2_rn(val.x, val.y);
            __half2 hi = __floats2half2_rn(val.z, val.w);
            __half2* dst = (__half2*)&dstb[((size_t)h0 * 256 + kloc0 + kj) * 8 + u4];
            dst[0] = lo;
            dst[1] = hi;
        }
    }
}

// ------------- Kernel B (fused): score + masked softmax + PV ----------------
// Best measured (R21, 53.0 us total): 2 q/block, grid 2048, 8 blocks/CU.
// h-split score (wave w = h-chunk [64w,64w+64), 4 guarded k-passes, 2-deep
// named k-prefetch of fp16 ek octets -- ONE b128 per 8-h window), LDS combine,
// wave softmax (masked p == 0 exactly), k-chunk PV (4-deep batched f32 V
// loads, p via readlane), LDS O-reduce.
__global__ __launch_bounds__(256, 8) void attn_kernel(const float* __restrict__ EQ,
                                                      const __half* __restrict__ EKT,
                                                      const float* __restrict__ wv,
                                                      const int* __restrict__ lens,
                                                      const float* __restrict__ V,
                                                      float* __restrict__ OUT) {
    const int b = blockIdx.y;
    const int q0 = blockIdx.x * 2;
    const int len = lens[b];

    __shared__ float eq_lds[2][256];    // 2 KB
    __shared__ float wv_lds[256];       // 1 KB
    __shared__ float shbuf[2048];       // 8 KB: score-partials, then O-partials
    __shared__ float maxb[4][2];
    __shared__ float sumb[4][2];

    const int tid = threadIdx.x;
    const int w = tid >> 6, lane = tid & 63;

    {
        if (tid < 128) {
            const float4* src = (const float4*)&EQ[((size_t)b * QN + q0) * HN];
            ((float4*)&eq_lds[0][0])[tid] = src[tid];
        }
        if (tid >= 192)
            *(float4*)&wv_lds[(tid - 192) << 2] = ((const float4*)wv)[tid - 192];
    }
    __syncthreads();

    // ---- score: wave w covers h in [64w, 64w+64); pass j covers k = 64j+lane
    float a00 = 0.f, a01 = 0.f;
    float a10 = 0.f, a11 = 0.f;
    float a20 = 0.f, a21 = 0.f;
    float a30 = 0.f, a31 = 0.f;

    const __half* ekb = EKT + (size_t)b * (32 * 256 * 8) + (size_t)(8 * w) * 2048;

#define WINDOW(KR, H8, A0, A1)                                                   \
    do {                                                                         \
        float2 k01 = h2f((KR).x);                                                \
        float2 k23 = h2f((KR).y);                                                \
        float2 k45 = h2f((KR).z);                                                \
        float2 k67 = h2f((KR).w);                                                \
        float4 wa = *(const float4*)&wv_lds[(H8)];                               \
        float4 wb = *(const float4*)&wv_lds[(H8) + 4];                           \
        float4 qa0 = *(const float4*)&eq_lds[0][(H8)];                           \
        float4 qb0 = *(const float4*)&eq_lds[0][(H8) + 4];                       \
        float4 qa1 = *(const float4*)&eq_lds[1][(H8)];                           \
        float4 qb1 = *(const float4*)&eq_lds[1][(H8) + 4];                       \
        A0 = fmaf(wa.x, __builtin_amdgcn_rcpf(fmaf(qa0.x, k01.x, 1.f)), A0);     \
        A0 = fmaf(wa.y, __builtin_amdgcn_rcpf(fmaf(qa0.y, k01.y, 1.f)), A0);     \
        A0 = fmaf(wa.z, __builtin_amdgcn_rcpf(fmaf(qa0.z, k23.x, 1.f)), A0);     \
        A0 = fmaf(wa.w, __builtin_amdgcn_rcpf(fmaf(qa0.w, k23.y, 1.f)), A0);     \
        A0 = fmaf(wb.x, __builtin_amdgcn_rcpf(fmaf(qb0.x, k45.x, 1.f)), A0);     \
        A0 = fmaf(wb.y, __builtin_amdgcn_rcpf(fmaf(qb0.y, k45.y, 1.f)), A0);     \
        A0 = fmaf(wb.z, __builtin_amdgcn_rcpf(fmaf(qb0.z, k67.x, 1.f)), A0);     \
        A0 = fmaf(wb.w, __builtin_amdgcn_rcpf(fmaf(qb0.w, k67.y, 1.f)), A0);     \
        A1 = fmaf(wa.x, __builtin_amdgcn_rcpf(fmaf(qa1.x, k01.x, 1.f)), A1);     \
        A1 = fmaf(wa.y, __builtin_amdgcn_rcpf(fmaf(qa1.y, k01.y, 1.f)), A1);     \
        A1 = fmaf(wa.z, __builtin_amdgcn_rcpf(fmaf(qa1.z, k23.x, 1.f)), A1);     \
        A1 = fmaf(wa.w, __builtin_amdgcn_rcpf(fmaf(qa1.w, k23.y, 1.f)), A1);     \
        A1 = fmaf(wb.x, __builtin_amdgcn_rcpf(fmaf(qb1.x, k45.x, 1.f)), A1);     \
        A1 = fmaf(wb.y, __builtin_amdgcn_rcpf(fmaf(qb1.y, k45.y, 1.f)), A1);     \
        A1 = fmaf(wb.z, __builtin_amdgcn_rcpf(fmaf(qb1.z, k67.x, 1.f)), A1);     \
        A1 = fmaf(wb.w, __builtin_amdgcn_rcpf(fmaf(qb1.w, k67.y, 1.f)), A1);     \
    } while (0)

#define PASS(J, A0, A1)                                                          \
    do {                                                                         \
        if ((J) * 64 < len) {                                                    \
            const __half* kp = ekb + (size_t)((J) * 64 + lane) * 8;              \
            uint4 kr0 = *(const uint4*)&kp[0];                                   \
            uint4 kr1;                                                          \
            _Pragma("unroll") for (int hw = 0; hw < 8; hw += 2) {                \
                kr1 = *(const uint4*)&kp[(size_t)(hw + 1) * 2048];               \
                WINDOW(kr0, (w << 6) + hw * 8, A0, A1);                          \
                if (hw + 2 < 8)                                                  \
                    kr0 = *(const uint4*)&kp[(size_t)(hw + 2) * 2048];           \
                WINDOW(kr1, (w << 6) + hw * 8 + 8, A0, A1);                      \
            }                                                                    \
        }                                                                        \
    } while (0)

    PASS(0, a00, a01);
    PASS(1, a10, a11);
    PASS(2, a20, a21);
    PASS(3, a30, a31);

    // store score partials: shbuf[((w*4 + j)*2 + q)*64 + lane]
    {
        float* sp = &shbuf[(size_t)(w << 3) * 64 + lane];
        sp[0 * 64] = a00; sp[1 * 64] = a01;
        sp[2 * 64] = a10; sp[3 * 64] = a11;
        sp[4 * 64] = a20; sp[5 * 64] = a21;
        sp[6 * 64] = a30; sp[7 * 64] = a31;
    }
    __syncthreads();

    // combine: wave w sums the 4 h-chunk partials for its k-chunk (j = w)
    const bool act = (w * 64) < len;
    float sum0 = 0.f, sum1 = 0.f;
    if (act) {
#pragma unroll
        for (int hc = 0; hc < 4; ++hc) {
            sum0 += shbuf[((hc * 4 + w) * 2 + 0) * 64 + lane];
            sum1 += shbuf[((hc * 4 + w) * 2 + 1) * 64 + lane];
        }
    }
    const bool kvalid = (w * 64 + lane) < len;
    float xs0 = kvalid ? (-2.f * sum0) : -1e6f;
    float xs1 = kvalid ? (-2.f * sum1) : -1e6f;

    float m0 = xs0, m1 = xs1;
#pragma unroll
    for (int off = 32; off; off >>= 1) {
        m0 = fmaxf(m0, __shfl_xor(m0, off, 64));
        m1 = fmaxf(m1, __shfl_xor(m1, off, 64));
    }
    if (lane == 0) { maxb[w][0] = m0; maxb[w][1] = m1; }
    __syncthreads();
    float g0 = fmaxf(fmaxf(maxb[0][0], maxb[1][0]), fmaxf(maxb[2][0], maxb[3][0]));
    float g1 = fmaxf(fmaxf(maxb[0][1], maxb[1][1]), fmaxf(maxb[2][1], maxb[3][1]));

    float p0 = __builtin_amdgcn_exp2f((xs0 - g0) * LOG2E);
    float p1 = __builtin_amdgcn_exp2f((xs1 - g1) * LOG2E);

    float s0 = p0, s1 = p1;
#pragma unroll
    for (int off = 32; off; off >>= 1) {
        s0 += __shfl_xor(s0, off, 64);
        s1 += __shfl_xor(s1, off, 64);
    }
    if (lane == 0) { sumb[w][0] = s0; sumb[w][1] = s1; }
    __syncthreads();
    float t0 = (sumb[0][0] + sumb[1][0]) + (sumb[2][0] + sumb[3][0]);
    float t1 = (sumb[0][1] + sumb[1][1]) + (sumb[2][1] + sumb[3][1]);
    p0 *= 1.f / t0;
    p1 *= 1.f / t1;

    // PV: wave w covers its 64 k rows (clamped to len); 4-deep batched V loads
    float4 op0 = make_float4(0.f, 0.f, 0.f, 0.f);
    float4 op1 = op0;
    if (act) {
        int kmax = len - w * 64;
        if (kmax > 64) kmax = 64;
        const float* vb = V + ((size_t)b * KN + (size_t)w * 64) * DN + (lane << 2);

#define PV_STEP(KK, VV)                                                        \
    do {                                                                       \
        float b0 = readlane_f(p0, (KK));                                       \
        float b1 = readlane_f(p1, (KK));                                       \
        op0.x = fmaf(b0, VV.x, op0.x); op0.y = fmaf(b0, VV.y, op0.y);          \
        op0.z = fmaf(b0, VV.z, op0.z); op0.w = fmaf(b0, VV.w, op0.w);          \
        op1.x = fmaf(b1, VV.x, op1.x); op1.y = fmaf(b1, VV.y, op1.y);          \
        op1.z = fmaf(b1, VV.z, op1.z); op1.w = fmaf(b1, VV.w, op1.w);          \
    } while (0)

        int kk = 0;
        for (; kk + 4 <= kmax; kk += 4) {
            float4 v0 = *(const float4*)&vb[(size_t)(kk + 0) * DN];
            float4 v1 = *(const float4*)&vb[(size_t)(kk + 1) * DN];
            float4 v2 = *(const float4*)&vb[(size_t)(kk + 2) * DN];
            float4 v3 = *(const float4*)&vb[(size_t)(kk + 3) * DN];
            PV_STEP(kk + 0, v0);
            PV_STEP(kk + 1, v1);
            PV_STEP(kk + 2, v2);
            PV_STEP(kk + 3, v3);
        }
        for (; kk < kmax; ++kk) {
            float4 v0 = *(const float4*)&vb[(size_t)kk * DN];
            PV_STEP(kk, v0);
        }
    }
    __syncthreads();   // score-partial reads done; shbuf reused for O-partials
    {
        const int d4 = lane << 2;
        *(float4*)&shbuf[((w << 1) + 0) * 256 + d4] = op0;
        *(float4*)&shbuf[((w << 1) + 1) * 256 + d4] = op1;
    }
    __syncthreads();

    if (tid < 128) {
        const int q = tid >> 6, ln = tid & 63;
        const int d4 = ln << 2;
        float4 r0 = *(const float4*)&shbuf[(0 * 2 + q) * 256 + d4];
        float4 r1 = *(const float4*)&shbuf[(1 * 2 + q) * 256 + d4];
        float4 r2 = *(const float4*)&shbuf[(2 * 2 + q) * 256 + d4];
        float4 r3 = *(const float4*)&shbuf[(3 * 2 + q) * 256 + d4];
        float4 r = make_float4((r0.x + r1.x) + (r2.x + r3.x),
                               (r0.y + r1.y) + (r2.y + r3.y),
                               (r0.z + r1.z) + (r2.z + r3.z),
                               (r0.w + r1.w) + (r2.w + r3.w));
        *(float4*)&OUT[((size_t)b * QN + q0 + q) * DN + d4] = r;
    }
}

extern "C" void kernel_launch(void* const* d_in, const int* in_sizes, int n_in,
                              void* d_out, int out_size, void* d_ws, size_t ws_size,
                              hipStream_t stream) {
    const float* queries = (const float*)d_in[0];
    const float* keys    = (const float*)d_in[1];
    const float* values  = (const float*)d_in[2];
    const int*   lens    = (const int*)d_in[3];
    const float* Wq      = (const float*)d_in[4];
    const float* Wk      = (const float*)d_in[5];
    const float* wv      = (const float*)d_in[6];
    float* out = (float*)d_out;

    float* eq   = (float*)d_ws;                          // [B,Q,H]    4 MB f32
    __half* ekT = (__half*)(eq + (size_t)B_ * QN * HN);  // [B,32,K,8] 2 MB fp16

    proj_kernel<<<(B_ * QN + B_ * KN) / 16, 256, 0, stream>>>(
        queries, keys, Wq, Wk, eq, ekT, TWOLOG2E);

    dim3 gB(QN / 2, B_);
    attn_kernel<<<gB, 256, 0, stream>>>(eq, ekT, wv, lens, values, out);
}